// Round 6
// baseline (117.668 us; speedup 1.0000x reference)
//
#include <hip/hip_runtime.h>
#include <math.h>

#define LN_EPS 1e-5f

typedef int   vint2   __attribute__((ext_vector_type(2)));
typedef float vfloat2 __attribute__((ext_vector_type(2)));

// ---------- DPP wave64 sum: 6 fused v_add_f32_dpp + 1 readlane ----------
template<int CTRL>
__device__ __forceinline__ float dppadd(float x) {
    int y = __builtin_amdgcn_update_dpp(0, __float_as_int(x), CTRL, 0xf, 0xf, true);
    return x + __int_as_float(y);
}
__device__ __forceinline__ float wave_sum(float x) {
    x = dppadd<0xB1>(x);
    x = dppadd<0x4E>(x);
    x = dppadd<0x141>(x);
    x = dppadd<0x140>(x);
    x = dppadd<0x142>(x);
    x = dppadd<0x143>(x);
    return __int_as_float(__builtin_amdgcn_readlane(__float_as_int(x), 63));
}

// tanh-form GELU via v_exp/v_rcp; max abs err ~3e-3 (threshold 0.63)
__device__ __forceinline__ float gelu_f(float x) {
    float t = x * fmaf(x * x, 0.044715f, 1.0f) * 1.5957691216057308f;
    float e = __expf(-t);
    return x * __builtin_amdgcn_rcpf(1.0f + e);
}

// Pack xy of both batches: xyp[n] = {x(b0,n), y(b0,n), x(b1,n), y(b1,n)}
__global__ __launch_bounds__(256) void pack_kernel(
    const float* __restrict__ stat, float4* __restrict__ xyp, int N)
{
    int n = blockIdx.x * blockDim.x + threadIdx.x;
    if (n >= N) return;
    float2 a = *reinterpret_cast<const float2*>(stat + (size_t)n * 16);
    float2 b = *reinterpret_cast<const float2*>(stat + (size_t)(n + N) * 16);
    xyp[n] = make_float4(a.x, a.y, b.x, b.y);
}

// h0 for rows r, r+1 (one wave): Linear(16->128) + GELU + LayerNorm + NT store
__device__ __forceinline__ void h0_pair(
    const float* __restrict__ stat, float* __restrict__ out,
    int r, int n_rows, const float (&w0)[16], const float (&w1)[16],
    float b0, float b1, float g0, float g1, float e0, float e1, int lane)
{
    if (r >= n_rows) return;
    const bool two = (r + 1 < n_rows);
    const int ra = __builtin_amdgcn_readfirstlane(r);
    const int rb = __builtin_amdgcn_readfirstlane(two ? r + 1 : r);
    const float4* srowA = reinterpret_cast<const float4*>(stat + (size_t)ra * 16);
    const float4* srowB = reinterpret_cast<const float4*>(stat + (size_t)rb * 16);
    float4 a0 = srowA[0], a1 = srowA[1], a2 = srowA[2], a3 = srowA[3];
    float4 c0 = srowB[0], c1 = srowB[1], c2 = srowB[2], c3 = srowB[3];
    float sA[16] = { a0.x,a0.y,a0.z,a0.w, a1.x,a1.y,a1.z,a1.w,
                     a2.x,a2.y,a2.z,a2.w, a3.x,a3.y,a3.z,a3.w };
    float sB[16] = { c0.x,c0.y,c0.z,c0.w, c1.x,c1.y,c1.z,c1.w,
                     c2.x,c2.y,c2.z,c2.w, c3.x,c3.y,c3.z,c3.w };

    float xA0 = b0, xA1 = b1, xB0 = b0, xB1 = b1;
#pragma unroll
    for (int c = 0; c < 16; ++c) {
        xA0 = fmaf(sA[c], w0[c], xA0);
        xA1 = fmaf(sA[c], w1[c], xA1);
        xB0 = fmaf(sB[c], w0[c], xB0);
        xB1 = fmaf(sB[c], w1[c], xB1);
    }
    xA0 = gelu_f(xA0); xA1 = gelu_f(xA1);
    xB0 = gelu_f(xB0); xB1 = gelu_f(xB1);

    const float sumA = wave_sum(xA0 + xA1);
    const float sqA  = wave_sum(xA0 * xA0 + xA1 * xA1);
    const float sumB = wave_sum(xB0 + xB1);
    const float sqB  = wave_sum(xB0 * xB0 + xB1 * xB1);

    const float muA = sumA * (1.0f / 128.0f);
    const float invA = rsqrtf(sqA * (1.0f / 128.0f) - muA * muA + LN_EPS);
    const float muB = sumB * (1.0f / 128.0f);
    const float invB = rsqrtf(sqB * (1.0f / 128.0f) - muB * muB + LN_EPS);

    float* orowA = out + (size_t)r * 128;
    __builtin_nontemporal_store((xA0 - muA) * invA * g0 + e0, orowA + lane);
    __builtin_nontemporal_store((xA1 - muA) * invA * g1 + e1, orowA + lane + 64);
    if (two) {
        float* orowB = out + (size_t)(r + 1) * 128;
        __builtin_nontemporal_store((xB0 - muB) * invB * g0 + e0, orowB + lane);
        __builtin_nontemporal_store((xB1 - muB) * invB * g1 + e1, orowB + lane + 64);
    }
}

// Wave-level pipelined fusion: every wave does 8 h0 rows AND every thread
// does 2 edges of det. det's long-latency loads are issued early and consumed
// between h0 row-pairs so gather latency hides under h0's VALU work.
__global__ __launch_bounds__(256) void fused2_kernel(
    const float* __restrict__ stat, const float* __restrict__ fc_w,
    const float* __restrict__ fc_b, const float* __restrict__ ln_g,
    const float* __restrict__ ln_b, float* __restrict__ out,
    const float4* __restrict__ xyp, const int* __restrict__ ei,
    float* __restrict__ det, int n_rows, int E)
{
    const int tid  = blockIdx.x * 256 + (int)threadIdx.x;
    const int lane = threadIdx.x & 63;
    const int wave = tid >> 6;

    // --- det stage 0: issue index loads (HBM latency hides under h0 pair 1)
    const int i2 = tid * 2;
    const bool has_det = (i2 + 1 < E);
    vint2 s = {0, 0}, d = {0, 0};
    if (has_det) {
        s = __builtin_nontemporal_load(reinterpret_cast<const vint2*>(ei + i2));
        d = __builtin_nontemporal_load(reinterpret_cast<const vint2*>(ei + E + i2));
    }

    // --- h0 setup: weights/params in registers
    float w0[16], w1[16];
#pragma unroll
    for (int c = 0; c < 16; ++c) {
        w0[c] = fc_w[c * 128 + lane];
        w1[c] = fc_w[c * 128 + lane + 64];
    }
    const float b0 = fc_b[lane], b1 = fc_b[lane + 64];
    const float g0 = ln_g[lane], g1 = ln_g[lane + 64];
    const float e0 = ln_b[lane], e1 = ln_b[lane + 64];

    const int r0 = wave * 8;

    // h0 pair 1 (index loads in flight)
    h0_pair(stat, out, r0, n_rows, w0, w1, b0, b1, g0, g1, e0, e1, lane);

    // --- det stage 1: issue the 4 gathers (L2-resident xyp)
    float4 gs0, gd0, gs1, gd1;
    if (has_det) {
        gs0 = xyp[s.x]; gd0 = xyp[d.x];
        gs1 = xyp[s.y]; gd1 = xyp[d.y];
    }

    // h0 pairs 2,3 (gathers in flight)
    h0_pair(stat, out, r0 + 2, n_rows, w0, w1, b0, b1, g0, g1, e0, e1, lane);
    h0_pair(stat, out, r0 + 4, n_rows, w0, w1, b0, b1, g0, g1, e0, e1, lane);

    // --- det stage 2: consume gathers, store
    if (has_det) {
        float dx, dy;
        vfloat2 o0, o1;
        dx = gs0.x - gd0.x; dy = gs0.y - gd0.y; o0.x = -0.5f * (dx*dx + dy*dy);
        dx = gs1.x - gd1.x; dy = gs1.y - gd1.y; o0.y = -0.5f * (dx*dx + dy*dy);
        dx = gs0.z - gd0.z; dy = gs0.w - gd0.w; o1.x = -0.5f * (dx*dx + dy*dy);
        dx = gs1.z - gd1.z; dy = gs1.w - gd1.w; o1.y = -0.5f * (dx*dx + dy*dy);
        __builtin_nontemporal_store(o0, reinterpret_cast<vfloat2*>(det + i2));
        __builtin_nontemporal_store(o1, reinterpret_cast<vfloat2*>(det + E + i2));
    }

    // h0 pair 4
    h0_pair(stat, out, r0 + 6, n_rows, w0, w1, b0, b1, g0, g1, e0, e1, lane);
}

// det-only tail (if E exceeds fused coverage) and ws-less fallback
__global__ __launch_bounds__(256) void det_kernel_direct(
    const float* __restrict__ stat, const int* __restrict__ ei,
    float* __restrict__ det, int E, int N, int i0)
{
    int i = i0 + (blockIdx.x * blockDim.x + threadIdx.x) * 2;
    if (i >= E) return;
    int2 s = *reinterpret_cast<const int2*>(ei + i);
    int2 d = *reinterpret_cast<const int2*>(ei + E + i);
#pragma unroll
    for (int b = 0; b < 2; ++b) {
        const float* base = stat + (size_t)b * N * 16;
        float2 ps0 = *reinterpret_cast<const float2*>(base + (size_t)s.x * 16);
        float2 pd0 = *reinterpret_cast<const float2*>(base + (size_t)d.x * 16);
        float2 ps1 = *reinterpret_cast<const float2*>(base + (size_t)s.y * 16);
        float2 pd1 = *reinterpret_cast<const float2*>(base + (size_t)d.y * 16);
        float dx0 = ps0.x - pd0.x, dy0 = ps0.y - pd0.y;
        float dx1 = ps1.x - pd1.x, dy1 = ps1.y - pd1.y;
        float2 v;
        v.x = -0.5f * (dx0 * dx0 + dy0 * dy0);
        v.y = -0.5f * (dx1 * dx1 + dy1 * dy1);
        *reinterpret_cast<float2*>(det + (size_t)b * E + i) = v;
    }
}

extern "C" void kernel_launch(void* const* d_in, const int* in_sizes, int n_in,
                              void* d_out, int out_size, void* d_ws, size_t ws_size,
                              hipStream_t stream) {
    const float* stat = (const float*)d_in[0];
    const int*   ei   = (const int*)d_in[1];
    const float* fc_w = (const float*)d_in[2];
    const float* fc_b = (const float*)d_in[3];
    const float* ln_g = (const float*)d_in[4];
    const float* ln_b = (const float*)d_in[5];
    float* out = (float*)d_out;

    const int n_rows = in_sizes[0] / 16;   // B*N = 100000
    const int E      = in_sizes[1] / 2;    // 1600000
    const int N      = n_rows / 2;         // B = 2

    float* H0  = out;
    float* det = out + (size_t)n_rows * 128;
    float* xyp = (float*)d_ws;
    const bool use_ws = (ws_size >= (size_t)N * 4 * sizeof(float)) && (E % 2 == 0);

    if (use_ws) {
        pack_kernel<<<(N + 255) / 256, 256, 0, stream>>>(stat, (float4*)xyp, N);
        // blocks sized to cover both jobs: 4 waves x 8 rows = 32 rows/block,
        // 256 threads x 2 edges = 512 edges/block. For the bench shape both
        // give exactly 3125 blocks.
        const int blocks_h = (n_rows + 31) / 32;
        const int blocks_d = (E / 2 + 255) / 256;
        const int G = blocks_h > blocks_d ? blocks_h : blocks_d;
        fused2_kernel<<<G, 256, 0, stream>>>(stat, fc_w, fc_b, ln_g, ln_b, H0,
                                             (const float4*)xyp, ei, det,
                                             n_rows, E);
        // tail if fused grid couldn't cover all edges (not hit for bench shape)
        const int covered = G * 512;
        if (covered < E) {
            const int rem_pairs = (E - covered + 1) / 2;
            det_kernel_direct<<<(rem_pairs + 255) / 256, 256, 0, stream>>>(
                stat, ei, det, E, N, covered);
        }
    } else {
        const int pairs = (E + 1) / 2;
        det_kernel_direct<<<(pairs + 255) / 256, 256, 0, stream>>>(stat, ei, det, E, N, 0);
        const int blocks_h = (n_rows + 31) / 32;
        fused2_kernel<<<blocks_h, 256, 0, stream>>>(stat, fc_w, fc_b, ln_g, ln_b, H0,
                                                    (const float4*)xyp, ei, det,
                                                    n_rows, 0 /*no det in fused*/);
    }
}

// Round 7
// 115.449 us; speedup vs baseline: 1.0192x; 1.0192x over previous
//
#include <hip/hip_runtime.h>
#include <math.h>

#define LN_EPS 1e-5f

typedef int   vint2   __attribute__((ext_vector_type(2)));
typedef float vfloat2 __attribute__((ext_vector_type(2)));

// ---------- DPP wave64 sum: 6 fused v_add_f32_dpp + 1 readlane ----------
template<int CTRL>
__device__ __forceinline__ float dppadd(float x) {
    int y = __builtin_amdgcn_update_dpp(0, __float_as_int(x), CTRL, 0xf, 0xf, true);
    return x + __int_as_float(y);
}
__device__ __forceinline__ float wave_sum(float x) {
    x = dppadd<0xB1>(x);
    x = dppadd<0x4E>(x);
    x = dppadd<0x141>(x);
    x = dppadd<0x140>(x);
    x = dppadd<0x142>(x);
    x = dppadd<0x143>(x);
    return __int_as_float(__builtin_amdgcn_readlane(__float_as_int(x), 63));
}

// tanh-form GELU via v_exp/v_rcp; max abs err ~3e-3 (threshold 0.63)
__device__ __forceinline__ float gelu_f(float x) {
    float t = x * fmaf(x * x, 0.044715f, 1.0f) * 1.5957691216057308f;
    float e = __expf(-t);
    return x * __builtin_amdgcn_rcpf(1.0f + e);
}

// Pack xy of both batches: xyp[n] = {x(b0,n), y(b0,n), x(b1,n), y(b1,n)}
__global__ __launch_bounds__(256) void pack_kernel(
    const float* __restrict__ stat, float4* __restrict__ xyp, int N)
{
    int n = blockIdx.x * blockDim.x + threadIdx.x;
    if (n >= N) return;
    float2 a = *reinterpret_cast<const float2*>(stat + (size_t)n * 16);
    float2 b = *reinterpret_cast<const float2*>(stat + (size_t)(n + N) * 16);
    xyp[n] = make_float4(a.x, a.y, b.x, b.y);
}

struct RowPair { float sA[16]; float sB[16]; };

// issue wave-uniform loads for rows r, r+1 (scalarized by readfirstlane)
__device__ __forceinline__ void load_pair(
    const float* __restrict__ stat, int r, int n_rows, RowPair& p)
{
    if (r >= n_rows) return;
    const bool two = (r + 1 < n_rows);
    const int ra = __builtin_amdgcn_readfirstlane(r);
    const int rb = __builtin_amdgcn_readfirstlane(two ? r + 1 : r);
    const float4* srowA = reinterpret_cast<const float4*>(stat + (size_t)ra * 16);
    const float4* srowB = reinterpret_cast<const float4*>(stat + (size_t)rb * 16);
    float4 a0 = srowA[0], a1 = srowA[1], a2 = srowA[2], a3 = srowA[3];
    float4 c0 = srowB[0], c1 = srowB[1], c2 = srowB[2], c3 = srowB[3];
    p.sA[0]=a0.x; p.sA[1]=a0.y; p.sA[2]=a0.z; p.sA[3]=a0.w;
    p.sA[4]=a1.x; p.sA[5]=a1.y; p.sA[6]=a1.z; p.sA[7]=a1.w;
    p.sA[8]=a2.x; p.sA[9]=a2.y; p.sA[10]=a2.z; p.sA[11]=a2.w;
    p.sA[12]=a3.x; p.sA[13]=a3.y; p.sA[14]=a3.z; p.sA[15]=a3.w;
    p.sB[0]=c0.x; p.sB[1]=c0.y; p.sB[2]=c0.z; p.sB[3]=c0.w;
    p.sB[4]=c1.x; p.sB[5]=c1.y; p.sB[6]=c1.z; p.sB[7]=c1.w;
    p.sB[8]=c2.x; p.sB[9]=c2.y; p.sB[10]=c2.z; p.sB[11]=c2.w;
    p.sB[12]=c3.x; p.sB[13]=c3.y; p.sB[14]=c3.z; p.sB[15]=c3.w;
}

__device__ __forceinline__ void compute_pair(
    float* __restrict__ out, const RowPair& p, int r, int n_rows,
    const float (&w0)[16], const float (&w1)[16],
    float b0, float b1, float g0, float g1, float e0, float e1, int lane)
{
    if (r >= n_rows) return;
    const bool two = (r + 1 < n_rows);

    float xA0 = b0, xA1 = b1, xB0 = b0, xB1 = b1;
#pragma unroll
    for (int c = 0; c < 16; ++c) {
        xA0 = fmaf(p.sA[c], w0[c], xA0);
        xA1 = fmaf(p.sA[c], w1[c], xA1);
        xB0 = fmaf(p.sB[c], w0[c], xB0);
        xB1 = fmaf(p.sB[c], w1[c], xB1);
    }
    xA0 = gelu_f(xA0); xA1 = gelu_f(xA1);
    xB0 = gelu_f(xB0); xB1 = gelu_f(xB1);

    const float sumA = wave_sum(xA0 + xA1);
    const float sqA  = wave_sum(xA0 * xA0 + xA1 * xA1);
    const float sumB = wave_sum(xB0 + xB1);
    const float sqB  = wave_sum(xB0 * xB0 + xB1 * xB1);

    const float muA = sumA * (1.0f / 128.0f);
    const float invA = rsqrtf(sqA * (1.0f / 128.0f) - muA * muA + LN_EPS);
    const float muB = sumB * (1.0f / 128.0f);
    const float invB = rsqrtf(sqB * (1.0f / 128.0f) - muB * muB + LN_EPS);

    float* orowA = out + (size_t)r * 128;
    __builtin_nontemporal_store((xA0 - muA) * invA * g0 + e0, orowA + lane);
    __builtin_nontemporal_store((xA1 - muA) * invA * g1 + e1, orowA + lane + 64);
    if (two) {
        float* orowB = out + (size_t)(r + 1) * 128;
        __builtin_nontemporal_store((xB0 - muB) * invB * g0 + e0, orowB + lane);
        __builtin_nontemporal_store((xB1 - muB) * invB * g1 + e1, orowB + lane + 64);
    }
}

// Wave-level pipelined fusion, row loads one pair ahead:
//   idx loads -> load P0 -> load P1 | compute P0 -> load P2 | compute P1
//   -> gathers -> load P3 | compute P2 -> det store -> compute P3
__global__ __launch_bounds__(256) void fused3_kernel(
    const float* __restrict__ stat, const float* __restrict__ fc_w,
    const float* __restrict__ fc_b, const float* __restrict__ ln_g,
    const float* __restrict__ ln_b, float* __restrict__ out,
    const float4* __restrict__ xyp, const int* __restrict__ ei,
    float* __restrict__ det, int n_rows, int E)
{
    const int tid  = blockIdx.x * 256 + (int)threadIdx.x;
    const int lane = threadIdx.x & 63;
    const int wave = tid >> 6;

    // det stage 0: index loads (HBM ~900cyc; hidden under pairs 0-1)
    const int i2 = tid * 2;
    const bool has_det = (i2 + 1 < E);
    vint2 s = {0, 0}, d = {0, 0};
    if (has_det) {
        s = __builtin_nontemporal_load(reinterpret_cast<const vint2*>(ei + i2));
        d = __builtin_nontemporal_load(reinterpret_cast<const vint2*>(ei + E + i2));
    }

    float w0[16], w1[16];
#pragma unroll
    for (int c = 0; c < 16; ++c) {
        w0[c] = fc_w[c * 128 + lane];
        w1[c] = fc_w[c * 128 + lane + 64];
    }
    const float b0 = fc_b[lane], b1 = fc_b[lane + 64];
    const float g0 = ln_g[lane], g1 = ln_g[lane + 64];
    const float e0 = ln_b[lane], e1 = ln_b[lane + 64];

    const int r0 = wave * 8;
    RowPair p0, p1, p2, p3;

    load_pair(stat, r0,     n_rows, p0);
    load_pair(stat, r0 + 2, n_rows, p1);
    compute_pair(out, p0, r0,     n_rows, w0, w1, b0, b1, g0, g1, e0, e1, lane);
    load_pair(stat, r0 + 4, n_rows, p2);
    compute_pair(out, p1, r0 + 2, n_rows, w0, w1, b0, b1, g0, g1, e0, e1, lane);

    // det stage 1: gathers (L2-resident xyp, ~200cyc; hidden under pair 2)
    float4 gs0, gd0, gs1, gd1;
    if (has_det) {
        gs0 = xyp[s.x]; gd0 = xyp[d.x];
        gs1 = xyp[s.y]; gd1 = xyp[d.y];
    }

    load_pair(stat, r0 + 6, n_rows, p3);
    compute_pair(out, p2, r0 + 4, n_rows, w0, w1, b0, b1, g0, g1, e0, e1, lane);

    // det stage 2: consume + NT store
    if (has_det) {
        float dx, dy;
        vfloat2 o0, o1;
        dx = gs0.x - gd0.x; dy = gs0.y - gd0.y; o0.x = -0.5f * (dx*dx + dy*dy);
        dx = gs1.x - gd1.x; dy = gs1.y - gd1.y; o0.y = -0.5f * (dx*dx + dy*dy);
        dx = gs0.z - gd0.z; dy = gs0.w - gd0.w; o1.x = -0.5f * (dx*dx + dy*dy);
        dx = gs1.z - gd1.z; dy = gs1.w - gd1.w; o1.y = -0.5f * (dx*dx + dy*dy);
        __builtin_nontemporal_store(o0, reinterpret_cast<vfloat2*>(det + i2));
        __builtin_nontemporal_store(o1, reinterpret_cast<vfloat2*>(det + E + i2));
    }

    compute_pair(out, p3, r0 + 6, n_rows, w0, w1, b0, b1, g0, g1, e0, e1, lane);
}

// det-only tail / ws-less fallback
__global__ __launch_bounds__(256) void det_kernel_direct(
    const float* __restrict__ stat, const int* __restrict__ ei,
    float* __restrict__ det, int E, int N, int i0)
{
    int i = i0 + (blockIdx.x * blockDim.x + threadIdx.x) * 2;
    if (i >= E) return;
    int2 s = *reinterpret_cast<const int2*>(ei + i);
    int2 d = *reinterpret_cast<const int2*>(ei + E + i);
#pragma unroll
    for (int b = 0; b < 2; ++b) {
        const float* base = stat + (size_t)b * N * 16;
        float2 ps0 = *reinterpret_cast<const float2*>(base + (size_t)s.x * 16);
        float2 pd0 = *reinterpret_cast<const float2*>(base + (size_t)d.x * 16);
        float2 ps1 = *reinterpret_cast<const float2*>(base + (size_t)s.y * 16);
        float2 pd1 = *reinterpret_cast<const float2*>(base + (size_t)d.y * 16);
        float dx0 = ps0.x - pd0.x, dy0 = ps0.y - pd0.y;
        float dx1 = ps1.x - pd1.x, dy1 = ps1.y - pd1.y;
        float2 v;
        v.x = -0.5f * (dx0 * dx0 + dy0 * dy0);
        v.y = -0.5f * (dx1 * dx1 + dy1 * dy1);
        *reinterpret_cast<float2*>(det + (size_t)b * E + i) = v;
    }
}

extern "C" void kernel_launch(void* const* d_in, const int* in_sizes, int n_in,
                              void* d_out, int out_size, void* d_ws, size_t ws_size,
                              hipStream_t stream) {
    const float* stat = (const float*)d_in[0];
    const int*   ei   = (const int*)d_in[1];
    const float* fc_w = (const float*)d_in[2];
    const float* fc_b = (const float*)d_in[3];
    const float* ln_g = (const float*)d_in[4];
    const float* ln_b = (const float*)d_in[5];
    float* out = (float*)d_out;

    const int n_rows = in_sizes[0] / 16;   // B*N = 100000
    const int E      = in_sizes[1] / 2;    // 1600000
    const int N      = n_rows / 2;         // B = 2

    float* H0  = out;
    float* det = out + (size_t)n_rows * 128;
    float* xyp = (float*)d_ws;
    const bool use_ws = (ws_size >= (size_t)N * 4 * sizeof(float)) && (E % 2 == 0);

    if (use_ws) {
        pack_kernel<<<(N + 255) / 256, 256, 0, stream>>>(stat, (float4*)xyp, N);
        const int blocks_h = (n_rows + 31) / 32;        // 32 rows/block
        const int blocks_d = (E / 2 + 255) / 256;       // 512 edges/block
        const int G = blocks_h > blocks_d ? blocks_h : blocks_d;
        fused3_kernel<<<G, 256, 0, stream>>>(stat, fc_w, fc_b, ln_g, ln_b, H0,
                                             (const float4*)xyp, ei, det,
                                             n_rows, E);
        const int covered = G * 512;
        if (covered < E) {
            const int rem_pairs = (E - covered + 1) / 2;
            det_kernel_direct<<<(rem_pairs + 255) / 256, 256, 0, stream>>>(
                stat, ei, det, E, N, covered);
        }
    } else {
        const int pairs = (E + 1) / 2;
        det_kernel_direct<<<(pairs + 255) / 256, 256, 0, stream>>>(stat, ei, det, E, N, 0);
        const int blocks_h = (n_rows + 31) / 32;
        fused3_kernel<<<blocks_h, 256, 0, stream>>>(stat, fc_w, fc_b, ln_g, ln_b, H0,
                                                    (const float4*)xyp, ei, det,
                                                    n_rows, 0);
    }
}